// Round 12
// baseline (216.824 us; speedup 1.0000x reference)
//
#include <hip/hip_runtime.h>
#include <cstdint>
#include <cstddef>

#define B_  16
#define N_  512
#define D_  256
#define H_  8
#define DK_ 32
// Round 12: r11 streaming attention + hi/lo split-precision P.
// r11 failed absmax 1.43e-2: rounding P to bf16 BEFORE normalization made the
// P-quantization term dominant. Fix: P = hi + lo (both bf16), PV uses two
// MFMAs -> attention-term rounding ~2^-17 (better than r10's 2^-9).
// Also: all LDS P accesses via short-vectors (TBAA-safe write->read ordering).

#define QKV_ELEMS 2097152   // B*N*D

__device__ __align__(16) unsigned short g_Qb[QKV_ELEMS];          // [B,H,N,DK] bf16
__device__ __align__(16) unsigned short g_Kb[QKV_ELEMS];          // [B,H,N,DK] bf16
__device__ __align__(16) unsigned short g_VT[QKV_ELEMS];          // [B,H,DK,N] bf16
__device__ __align__(16) unsigned short g_STb[(size_t)B_*N_*N_];  // [B,N,N] bf16
__device__ __align__(16) unsigned short g_WoB[D_*D_];             // Wo bf16

typedef short v8s __attribute__((ext_vector_type(8)));
typedef short v4s __attribute__((ext_vector_type(4)));
typedef float v4f __attribute__((ext_vector_type(4)));

__device__ __forceinline__ unsigned short f2b(float f){
  unsigned int x;
  __builtin_memcpy(&x, &f, 4);
  x = x + 0x7FFFu + ((x >> 16) & 1u);   // round-to-nearest-even
  return (unsigned short)(x >> 16);
}

#if defined(__has_builtin)
#if __has_builtin(__builtin_amdgcn_cvt_pk_bf16_f32)
#define PK_BF16 1
#endif
#endif

__device__ __forceinline__ unsigned int pk2(float a, float b){
#ifdef PK_BF16
  typedef __bf16 v2bf __attribute__((ext_vector_type(2)));
  v2bf r = __builtin_amdgcn_cvt_pk_bf16_f32(a, b);
  unsigned int u;
  __builtin_memcpy(&u, &r, 4);
  return u;
#else
  return (unsigned int)f2b(a) | ((unsigned int)f2b(b) << 16);
#endif
}
__device__ __forceinline__ v8s pk8(const float4 a, const float4 b){
  union { unsigned int u[4]; v8s v; } x;
  x.u[0] = pk2(a.x, a.y); x.u[1] = pk2(a.z, a.w);
  x.u[2] = pk2(b.x, b.y); x.u[3] = pk2(b.z, b.w);
  return x.v;
}
// float value of the bf16 stored in low/high half of a packed u32
__device__ __forceinline__ float lo16f(unsigned int u){
  const unsigned int x = u << 16;
  float f; __builtin_memcpy(&f, &x, 4); return f;
}
__device__ __forceinline__ float hi16f(unsigned int u){
  const unsigned int x = u & 0xFFFF0000u;
  float f; __builtin_memcpy(&f, &x, 4); return f;
}

// ---------------------------------------------------------------------------
// Dispatch 1: [0,1536) QKV GEMMs; [1536,3584) stats; [3584,3648) Wo conv.
// GEMM: C[m][n] = sum_k A[m][k]*W[n][k] + b[n], M=8192, N=K=256; wave=16mx64n.
// A/W frags: 2xfloat4 + inline pack to bf16 (no LDS, no barrier).
// z==2 (V): operands swapped -> D[n][tok] -> coalesced transposed store.
// ---------------------------------------------------------------------------
__global__ __launch_bounds__(256) void fused_mid(
    const float* __restrict__ query, const float* __restrict__ key_,
    const float* __restrict__ value, const float* __restrict__ dist,
    const float* __restrict__ adjm,  const int* __restrict__ mask,
    const float* __restrict__ Wq, const float* __restrict__ Wk,
    const float* __restrict__ Wv, const float* __restrict__ Wo,
    const float* __restrict__ bq, const float* __restrict__ bk,
    const float* __restrict__ bv)
{
  const int bid = blockIdx.x;
  const int t   = threadIdx.x;
  const int w = t >> 6, lane = t & 63, kl = lane & 15, quad = lane >> 4;

  if (bid < 1536){
    const int z  = bid >> 9;                 // 0:Q 1:K 2:V
    const int rr = bid & 511;
    const int mt = rr >> 2, nt = rr & 3;     // nt fastest: A-tile L2 sharing
    const float* Ap = (z==0) ? query : (z==1) ? key_ : value;
    const float* Wp = (z==0) ? Wq : (z==1) ? Wk : Wv;
    const float* bp = (z==0) ? bq : (z==1) ? bk : bv;
    const int m0 = mt*64 + w*16;
    const int n0 = nt*64;

    v4f acc[4];
    #pragma unroll
    for (int nb = 0; nb < 4; ++nb) acc[nb] = (v4f){0.f,0.f,0.f,0.f};
    const int arow = m0 + kl;

    #pragma unroll
    for (int k0 = 0; k0 < 256; k0 += 32){
      const float* ap = Ap + (size_t)arow*256 + k0 + quad*8;
      const v8s af = pk8(reinterpret_cast<const float4*>(ap)[0],
                         reinterpret_cast<const float4*>(ap)[1]);
      #pragma unroll
      for (int nb = 0; nb < 4; ++nb){
        const float* wp = Wp + (size_t)(n0 + nb*16 + kl)*256 + k0 + quad*8;
        const v8s wf = pk8(reinterpret_cast<const float4*>(wp)[0],
                           reinterpret_cast<const float4*>(wp)[1]);
        if (z == 2)
          acc[nb] = __builtin_amdgcn_mfma_f32_16x16x32_bf16(wf, af, acc[nb], 0, 0, 0);
        else
          acc[nb] = __builtin_amdgcn_mfma_f32_16x16x32_bf16(af, wf, acc[nb], 0, 0, 0);
      }
    }

    if (z == 2){
      const int tok = m0 + kl, bb = tok >> 9, nr = tok & 511;
      #pragma unroll
      for (int nb = 0; nb < 4; ++nb)
        #pragma unroll
        for (int r = 0; r < 4; ++r){
          const int n = n0 + nb*16 + quad*4 + r;
          const float v = acc[nb][r] + bp[n];
          g_VT[(((size_t)bb*H_ + (n>>5))*DK_ + (n&31))*N_ + nr] = f2b(v);
        }
    } else {
      unsigned short* dst = z ? g_Kb : g_Qb;
      #pragma unroll
      for (int nb = 0; nb < 4; ++nb){
        const int n = n0 + nb*16 + kl;
        const float bias = bp[n];
        #pragma unroll
        for (int r = 0; r < 4; ++r){
          const int m = m0 + quad*4 + r;
          const float v = acc[nb][r] + bias;
          dst[(((size_t)(m>>9)*H_ + (n>>5))*N_ + (m&511))*DK_ + (n&31)] = f2b(v);
        }
      }
    }
    return;
  }

  if (bid < 3584){
    // ---- stats: row = (bid-1536)*4 + w; 64 lanes x 8 elems; wave reduce ----
    const int row = (bid - 1536)*4 + w;      // b*512 + q
    const int b   = row >> 9;
    const size_t roff = (size_t)row*N_ + lane*8;
    const float4 d0 = *reinterpret_cast<const float4*>(dist + roff);
    const float4 d1 = *reinterpret_cast<const float4*>(dist + roff + 4);
    const float4 a0 = *reinterpret_cast<const float4*>(adjm + roff);
    const float4 a1 = *reinterpret_cast<const float4*>(adjm + roff + 4);
    const int4   m0v = *reinterpret_cast<const int4*>(mask + b*N_ + lane*8);
    const int4   m1v = *reinterpret_cast<const int4*>(mask + b*N_ + lane*8 + 4);
    float e[8], a[8];
    e[0] = m0v.x ? __expf(-d0.x) : 0.f;  e[1] = m0v.y ? __expf(-d0.y) : 0.f;
    e[2] = m0v.z ? __expf(-d0.z) : 0.f;  e[3] = m0v.w ? __expf(-d0.w) : 0.f;
    e[4] = m1v.x ? __expf(-d1.x) : 0.f;  e[5] = m1v.y ? __expf(-d1.y) : 0.f;
    e[6] = m1v.z ? __expf(-d1.z) : 0.f;  e[7] = m1v.w ? __expf(-d1.w) : 0.f;
    a[0]=a0.x; a[1]=a0.y; a[2]=a0.z; a[3]=a0.w;
    a[4]=a1.x; a[5]=a1.y; a[6]=a1.z; a[7]=a1.w;
    float lz = 0.f, la = 0.f;
    #pragma unroll
    for (int i = 0; i < 8; ++i){ lz += e[i]; la += a[i]; }
    #pragma unroll
    for (int o = 1; o < 64; o <<= 1){
      lz += __shfl_xor(lz, o, 64);
      la += __shfl_xor(la, o, 64);
    }
    const float c0 = (lz > 0.f) ? 0.3f / lz : 0.f;
    const float c1 = 0.4f / (la + 1e-6f);
    uint4 o4;
    o4.x = pk2(e[0]*c0 + a[0]*c1, e[1]*c0 + a[1]*c1);
    o4.y = pk2(e[2]*c0 + a[2]*c1, e[3]*c0 + a[3]*c1);
    o4.z = pk2(e[4]*c0 + a[4]*c1, e[5]*c0 + a[5]*c1);
    o4.w = pk2(e[6]*c0 + a[6]*c1, e[7]*c0 + a[7]*c1);
    *reinterpret_cast<uint4*>(g_STb + roff) = o4;
    return;
  }

  // ---- Wo fp32 -> bf16 (64 blocks x 256 thr x 4) ----
  {
    const int i = ((bid - 3584)*256 + t)*4;
    const float4 u = *reinterpret_cast<const float4*>(Wo + i);
    uint2 o2;
    o2.x = pk2(u.x, u.y);
    o2.y = pk2(u.z, u.w);
    *reinterpret_cast<uint2*>(g_WoB + i) = o2;
  }
}

// ---------------------------------------------------------------------------
// Dispatch 2: streaming attention. 512 thr = 8 waves = 8 heads; one (b,qtile).
// Per chunk c (32 keys): S^T = mfma(K,Q) -> exp (no max-sub) -> hi/lo bf16
// split -> LDS (v4s writes, v8s reads; row = [32 hi | 8 pad | 32 lo]) ->
// o += V*hi + V*lo (unnormalized), s += V*ST. Final O = o*(0.3/psum) + s.
// Then fused Wo projection from LDS X tile.
// ---------------------------------------------------------------------------
__global__ __launch_bounds__(512) void attn_kernel(
    const int* __restrict__ mask, const float* __restrict__ bo,
    float* __restrict__ out)
{
  __shared__ unsigned short Pl[8*16*80];    // 20.5 KB: per-wave 16q x (32hi|8pad|32lo)
  __shared__ unsigned short Xl[16*264];     //  8.4 KB: X[qrow][n] bf16
  const int bid = blockIdx.x;
  const int b  = bid & 15;                  // same-b -> same XCD (L2 K/V/ST reuse)
  const int qt = bid >> 4;
  const int q0 = qt*16;
  const int t  = threadIdx.x;
  const int w  = t >> 6, lane = t & 63;
  const int kl = lane & 15, quad = lane >> 4;
  const int h  = w;
  const size_t bh = (size_t)b*H_ + h;
  const float scale = 0.17677669529663687f;   // 1/sqrt(32)

  const unsigned short* Qp = g_Qb + (bh*N_ + q0)*DK_;
  const unsigned short* Kp = g_Kb + bh*N_*DK_;
  const unsigned short* Vp = g_VT + bh*DK_*N_;
  const unsigned short* Sp = g_STb + ((size_t)(b*N_ + q0))*N_;
  const int* mrow = mask + b*N_;
  const v4f vz = {0.f, 0.f, 0.f, 0.f};

  // Q B-frag: B[d=quad*8+j][q=kl] = Q[q0+kl][quad*8+j]
  const v8s aq = *reinterpret_cast<const v8s*>(Qp + (size_t)kl*DK_ + quad*8);

  unsigned short* Pw = Pl + w*1280;
  v4f o0 = vz, o1 = vz;     // unnormalized sum exp(s)*V  (hi+lo exact)
  v4f s0 = vz, s1 = vz;     // ST*V
  float psum = 0.f;

  #pragma unroll
  for (int c = 0; c < 16; ++c){
    // ---- S^T chunk: keys c*32 + [0,32) ----
    const v8s ak0 = *reinterpret_cast<const v8s*>(Kp + (size_t)(c*32 +      kl)*DK_ + quad*8);
    const v8s ak1 = *reinterpret_cast<const v8s*>(Kp + (size_t)(c*32 + 16 + kl)*DK_ + quad*8);
    v4f t0 = __builtin_amdgcn_mfma_f32_16x16x32_bf16(ak0, aq, vz, 0, 0, 0);
    v4f t1 = __builtin_amdgcn_mfma_f32_16x16x32_bf16(ak1, aq, vz, 0, 0, 0);

    // lane holds S^T[key = c*32 + 16*blk + quad*4 + r][q = kl]
    const int4 mv0 = reinterpret_cast<const int4*>(mrow + c*32)[quad];
    const int4 mv1 = reinterpret_cast<const int4*>(mrow + c*32 + 16)[quad];
    t0[0] = mv0.x ? __expf(t0[0]*scale) : 0.f;
    t0[1] = mv0.y ? __expf(t0[1]*scale) : 0.f;
    t0[2] = mv0.z ? __expf(t0[2]*scale) : 0.f;
    t0[3] = mv0.w ? __expf(t0[3]*scale) : 0.f;
    t1[0] = mv1.x ? __expf(t1[0]*scale) : 0.f;
    t1[1] = mv1.y ? __expf(t1[1]*scale) : 0.f;
    t1[2] = mv1.z ? __expf(t1[2]*scale) : 0.f;
    t1[3] = mv1.w ? __expf(t1[3]*scale) : 0.f;
    psum += (t0[0]+t0[1]) + (t0[2]+t0[3]) + (t1[0]+t1[1]) + (t1[2]+t1[3]);

    // ---- hi/lo bf16 split: p = hi + lo, |err| ~ 2^-18 * p ----
    const unsigned int h00 = pk2(t0[0], t0[1]);
    const unsigned int h01 = pk2(t0[2], t0[3]);
    const unsigned int h10 = pk2(t1[0], t1[1]);
    const unsigned int h11 = pk2(t1[2], t1[3]);
    const unsigned int l00 = pk2(t0[0] - lo16f(h00), t0[1] - hi16f(h00));
    const unsigned int l01 = pk2(t0[2] - lo16f(h01), t0[3] - hi16f(h01));
    const unsigned int l10 = pk2(t1[0] - lo16f(h10), t1[1] - hi16f(h10));
    const unsigned int l11 = pk2(t1[2] - lo16f(h11), t1[3] - hi16f(h11));

    // ---- transpose through LDS; SAME elem type (short vecs) for TBAA order ----
    {
      union { unsigned int u[2]; v4s v; } wv;
      wv.u[0] = h00; wv.u[1] = h01;
      *reinterpret_cast<v4s*>(&Pw[kl*80 + quad*4])      = wv.v;
      wv.u[0] = h10; wv.u[1] = h11;
      *reinterpret_cast<v4s*>(&Pw[kl*80 + 16 + quad*4]) = wv.v;
      wv.u[0] = l00; wv.u[1] = l01;
      *reinterpret_cast<v4s*>(&Pw[kl*80 + 40 + quad*4])      = wv.v;
      wv.u[0] = l10; wv.u[1] = l11;
      *reinterpret_cast<v4s*>(&Pw[kl*80 + 40 + 16 + quad*4]) = wv.v;
    }
    // B-frags: P[q=kl][key = c*32 + quad*8 + j]  (same-wave, lgkm-ordered)
    const v8s bph = *reinterpret_cast<const v8s*>(&Pw[kl*80 + quad*8]);
    const v8s bpl = *reinterpret_cast<const v8s*>(&Pw[kl*80 + 40 + quad*8]);
    const v8s bst = *reinterpret_cast<const v8s*>(Sp + (size_t)kl*N_ + c*32 + quad*8);
    const v8s av0 = *reinterpret_cast<const v8s*>(Vp + (size_t)(     kl)*N_ + c*32 + quad*8);
    const v8s av1 = *reinterpret_cast<const v8s*>(Vp + (size_t)(16 + kl)*N_ + c*32 + quad*8);
    o0 = __builtin_amdgcn_mfma_f32_16x16x32_bf16(av0, bph, o0, 0, 0, 0);
    o0 = __builtin_amdgcn_mfma_f32_16x16x32_bf16(av0, bpl, o0, 0, 0, 0);
    s0 = __builtin_amdgcn_mfma_f32_16x16x32_bf16(av0, bst, s0, 0, 0, 0);
    o1 = __builtin_amdgcn_mfma_f32_16x16x32_bf16(av1, bph, o1, 0, 0, 0);
    o1 = __builtin_amdgcn_mfma_f32_16x16x32_bf16(av1, bpl, o1, 0, 0, 0);
    s1 = __builtin_amdgcn_mfma_f32_16x16x32_bf16(av1, bst, s1, 0, 0, 0);
  }

  // ---- column sum over q=kl (lanes kl, kl+16, kl+32, kl+48), then scale ----
  psum += __shfl_xor(psum, 16, 64);
  psum += __shfl_xor(psum, 32, 64);
  const float inv = (psum > 0.f) ? 0.3f / psum : 0.f;
  #pragma unroll
  for (int r = 0; r < 4; ++r){
    o0[r] = o0[r]*inv + s0[r];
    o1[r] = o1[r]*inv + s1[r];
  }

  // ---- X[q=kl][h*32 + d'] bf16 into LDS (lane holds O^T[d'=quad*4+r][q=kl]) ----
  {
    unsigned short* xr = Xl + kl*264 + h*32;
    *reinterpret_cast<unsigned int*>(&xr[quad*4])          = pk2(o0[0], o0[1]);
    *reinterpret_cast<unsigned int*>(&xr[quad*4 + 2])      = pk2(o0[2], o0[3]);
    *reinterpret_cast<unsigned int*>(&xr[16 + quad*4])     = pk2(o1[0], o1[1]);
    *reinterpret_cast<unsigned int*>(&xr[16 + quad*4 + 2]) = pk2(o1[2], o1[3]);
  }
  __syncthreads();

  // ---- Phase C: out = X @ Wo^T + bo; wave w -> n in [w*32, w*32+32) ----
  {
    const int n0 = w*32;
    v4f a20 = vz, a21 = vz;
    #pragma unroll
    for (int k0 = 0; k0 < 256; k0 += 32){
      const v8s af  = *reinterpret_cast<const v8s*>(&Xl[kl*264 + k0 + quad*8]);
      const v8s wf0 = *reinterpret_cast<const v8s*>(g_WoB + (size_t)(n0 + kl)*256 + k0 + quad*8);
      const v8s wf1 = *reinterpret_cast<const v8s*>(g_WoB + (size_t)(n0 + 16 + kl)*256 + k0 + quad*8);
      a20 = __builtin_amdgcn_mfma_f32_16x16x32_bf16(af, wf0, a20, 0, 0, 0);
      a21 = __builtin_amdgcn_mfma_f32_16x16x32_bf16(af, wf1, a21, 0, 0, 0);
    }
    const int n_0 = n0 + kl, n_1 = n0 + 16 + kl;
    const float b0v = bo[n_0], b1v = bo[n_1];
    #pragma unroll
    for (int r = 0; r < 4; ++r){
      const size_t m = (size_t)(b*N_ + q0 + quad*4 + r);
      out[m*256 + n_0] = a20[r] + b0v;
      out[m*256 + n_1] = a21[r] + b1v;
    }
  }
}

extern "C" void kernel_launch(void* const* d_in, const int* in_sizes, int n_in,
                              void* d_out, int out_size, void* d_ws, size_t ws_size,
                              hipStream_t stream)
{
  const float* query = (const float*)d_in[0];
  const float* key_  = (const float*)d_in[1];
  const float* value = (const float*)d_in[2];
  const float* adjm  = (const float*)d_in[3];
  const float* dist  = (const float*)d_in[4];
  // d_in[5] = edges_att (unused)
  const int*   mask  = (const int*)d_in[6];
  const float* Wq = (const float*)d_in[7];  const float* bq = (const float*)d_in[8];
  const float* Wk = (const float*)d_in[9];  const float* bk = (const float*)d_in[10];
  const float* Wv = (const float*)d_in[11]; const float* bv = (const float*)d_in[12];
  const float* Wo = (const float*)d_in[13]; const float* bo = (const float*)d_in[14];

  fused_mid<<<3648, 256, 0, stream>>>(query, key_, value, dist, adjm, mask,
                                      Wq, Wk, Wv, Wo, bq, bk, bv);
  attn_kernel<<<512, 512, 0, stream>>>(mask, bo, (float*)d_out);
}

// Round 13
// 197.543 us; speedup vs baseline: 1.0976x; 1.0976x over previous
//
#include <hip/hip_runtime.h>
#include <cstdint>
#include <cstddef>

#define B_  16
#define N_  512
#define D_  256
#define H_  8
#define DK_ 32
// Round 13: best-of recombination.
//  1) conv_w: all 4 weight matrices fp32->bf16 into g_Wb (own dispatch:
//     same-dispatch readers would race).
//  2) fused_mid: QKV MFMA GEMMs with W-frags as direct v8s from g_Wb (r10:
//     <55us; r12's inline fp32 W repack cost +25us) + XCD-aware swizzle:
//     blocks sharing an A-tile are 8 apart in bid -> same XCD L2.
//     stats one-row-per-wave (no LDS).
//  3) attn: r12 streaming hi/lo kernel (accuracy-proven 2e-3), Wo from g_Wb.

#define QKV_ELEMS 2097152   // B*N*D

__device__ __align__(16) unsigned short g_Qb[QKV_ELEMS];          // [B,H,N,DK] bf16
__device__ __align__(16) unsigned short g_Kb[QKV_ELEMS];          // [B,H,N,DK] bf16
__device__ __align__(16) unsigned short g_VT[QKV_ELEMS];          // [B,H,DK,N] bf16
__device__ __align__(16) unsigned short g_STb[(size_t)B_*N_*N_];  // [B,N,N] bf16
__device__ __align__(16) unsigned short g_Wb[4*D_*D_];            // Wq,Wk,Wv,Wo bf16

typedef short v8s __attribute__((ext_vector_type(8)));
typedef short v4s __attribute__((ext_vector_type(4)));
typedef float v4f __attribute__((ext_vector_type(4)));

__device__ __forceinline__ unsigned short f2b(float f){
  unsigned int x;
  __builtin_memcpy(&x, &f, 4);
  x = x + 0x7FFFu + ((x >> 16) & 1u);   // round-to-nearest-even
  return (unsigned short)(x >> 16);
}

#if defined(__has_builtin)
#if __has_builtin(__builtin_amdgcn_cvt_pk_bf16_f32)
#define PK_BF16 1
#endif
#endif

__device__ __forceinline__ unsigned int pk2(float a, float b){
#ifdef PK_BF16
  typedef __bf16 v2bf __attribute__((ext_vector_type(2)));
  v2bf r = __builtin_amdgcn_cvt_pk_bf16_f32(a, b);
  unsigned int u;
  __builtin_memcpy(&u, &r, 4);
  return u;
#else
  return (unsigned int)f2b(a) | ((unsigned int)f2b(b) << 16);
#endif
}
__device__ __forceinline__ v8s pk8(const float4 a, const float4 b){
  union { unsigned int u[4]; v8s v; } x;
  x.u[0] = pk2(a.x, a.y); x.u[1] = pk2(a.z, a.w);
  x.u[2] = pk2(b.x, b.y); x.u[3] = pk2(b.z, b.w);
  return x.v;
}
// float value of the bf16 stored in low/high half of a packed u32
__device__ __forceinline__ float lo16f(unsigned int u){
  const unsigned int x = u << 16;
  float f; __builtin_memcpy(&f, &x, 4); return f;
}
__device__ __forceinline__ float hi16f(unsigned int u){
  const unsigned int x = u & 0xFFFF0000u;
  float f; __builtin_memcpy(&f, &x, 4); return f;
}

// ---------------------------------------------------------------------------
// Dispatch 1: weights fp32 -> bf16. 256 blocks (64 per matrix) x 256 thr x 4.
// ---------------------------------------------------------------------------
__global__ __launch_bounds__(256) void conv_w(
    const float* __restrict__ Wq, const float* __restrict__ Wk,
    const float* __restrict__ Wv, const float* __restrict__ Wo)
{
  const int widx = blockIdx.x >> 6;
  const int i = ((blockIdx.x & 63)*256 + threadIdx.x)*4;
  const float* src = (widx==0) ? Wq : (widx==1) ? Wk : (widx==2) ? Wv : Wo;
  const float4 u = *reinterpret_cast<const float4*>(src + i);
  uint2 o2;
  o2.x = pk2(u.x, u.y);
  o2.y = pk2(u.z, u.w);
  *reinterpret_cast<uint2*>(g_Wb + widx*65536 + i) = o2;
}

// ---------------------------------------------------------------------------
// Dispatch 2: blocks [0,1536): QKV MFMA GEMMs; [1536,3584): stats (1 row/wave).
// GEMM: C[m][n] = sum_k A[m][k]*W[n][k] + b[n], M=8192, N=K=256; wave=16mx64n.
// XCD swizzle: r=bid&511 -> mt=(r&7)*16+(r>>5), nt=(r>>3)&3: the 4 blocks
// sharing A-tile mt are bid+{0,8,16,24} -> same XCD (bid%8) -> A L2-resident.
// A-frag: 2xfloat4+pack. W-frag: direct v8s from g_Wb (bf16, L2-hot).
// z==2 (V): operands swapped -> D[n][tok] -> coalesced transposed store.
// ---------------------------------------------------------------------------
__global__ __launch_bounds__(256) void fused_mid(
    const float* __restrict__ query, const float* __restrict__ key_,
    const float* __restrict__ value, const float* __restrict__ dist,
    const float* __restrict__ adjm,  const int* __restrict__ mask,
    const float* __restrict__ bq, const float* __restrict__ bk,
    const float* __restrict__ bv)
{
  const int bid = blockIdx.x;
  const int t   = threadIdx.x;
  const int w = t >> 6, lane = t & 63, kl = lane & 15, quad = lane >> 4;

  if (bid < 1536){
    const int z  = bid >> 9;                 // 0:Q 1:K 2:V
    const int r_ = bid & 511;
    const int mt = (r_ & 7)*16 + (r_ >> 5);  // 0..127
    const int nt = (r_ >> 3) & 3;            // 0..3
    const float* Ap = (z==0) ? query : (z==1) ? key_ : value;
    const float* bp = (z==0) ? bq : (z==1) ? bk : bv;
    const unsigned short* Wb = g_Wb + z*65536;
    const int m0 = mt*64 + w*16;
    const int n0 = nt*64;

    v4f acc[4];
    #pragma unroll
    for (int nb = 0; nb < 4; ++nb) acc[nb] = (v4f){0.f,0.f,0.f,0.f};
    const int arow = m0 + kl;

    #pragma unroll
    for (int k0 = 0; k0 < 256; k0 += 32){
      const float* ap = Ap + (size_t)arow*256 + k0 + quad*8;
      const v8s af = pk8(reinterpret_cast<const float4*>(ap)[0],
                         reinterpret_cast<const float4*>(ap)[1]);
      #pragma unroll
      for (int nb = 0; nb < 4; ++nb){
        const v8s wf = *reinterpret_cast<const v8s*>(
            Wb + (size_t)(n0 + nb*16 + kl)*256 + k0 + quad*8);
        if (z == 2)
          acc[nb] = __builtin_amdgcn_mfma_f32_16x16x32_bf16(wf, af, acc[nb], 0, 0, 0);
        else
          acc[nb] = __builtin_amdgcn_mfma_f32_16x16x32_bf16(af, wf, acc[nb], 0, 0, 0);
      }
    }

    if (z == 2){
      const int tok = m0 + kl, bb = tok >> 9, nr = tok & 511;
      #pragma unroll
      for (int nb = 0; nb < 4; ++nb)
        #pragma unroll
        for (int r = 0; r < 4; ++r){
          const int n = n0 + nb*16 + quad*4 + r;
          const float v = acc[nb][r] + bp[n];
          g_VT[(((size_t)bb*H_ + (n>>5))*DK_ + (n&31))*N_ + nr] = f2b(v);
        }
    } else {
      unsigned short* dst = z ? g_Kb : g_Qb;
      #pragma unroll
      for (int nb = 0; nb < 4; ++nb){
        const int n = n0 + nb*16 + kl;
        const float bias = bp[n];
        #pragma unroll
        for (int r = 0; r < 4; ++r){
          const int m = m0 + quad*4 + r;
          const float v = acc[nb][r] + bias;
          dst[(((size_t)(m>>9)*H_ + (n>>5))*N_ + (m&511))*DK_ + (n&31)] = f2b(v);
        }
      }
    }
    return;
  }

  // ---- stats: row = (bid-1536)*4 + w; 64 lanes x 8 elems; wave reduce ----
  {
    const int row = (bid - 1536)*4 + w;      // b*512 + q
    const int b   = row >> 9;
    const size_t roff = (size_t)row*N_ + lane*8;
    const float4 d0 = *reinterpret_cast<const float4*>(dist + roff);
    const float4 d1 = *reinterpret_cast<const float4*>(dist + roff + 4);
    const float4 a0 = *reinterpret_cast<const float4*>(adjm + roff);
    const float4 a1 = *reinterpret_cast<const float4*>(adjm + roff + 4);
    const int4   m0v = *reinterpret_cast<const int4*>(mask + b*N_ + lane*8);
    const int4   m1v = *reinterpret_cast<const int4*>(mask + b*N_ + lane*8 + 4);
    float e[8], a[8];
    e[0] = m0v.x ? __expf(-d0.x) : 0.f;  e[1] = m0v.y ? __expf(-d0.y) : 0.f;
    e[2] = m0v.z ? __expf(-d0.z) : 0.f;  e[3] = m0v.w ? __expf(-d0.w) : 0.f;
    e[4] = m1v.x ? __expf(-d1.x) : 0.f;  e[5] = m1v.y ? __expf(-d1.y) : 0.f;
    e[6] = m1v.z ? __expf(-d1.z) : 0.f;  e[7] = m1v.w ? __expf(-d1.w) : 0.f;
    a[0]=a0.x; a[1]=a0.y; a[2]=a0.z; a[3]=a0.w;
    a[4]=a1.x; a[5]=a1.y; a[6]=a1.z; a[7]=a1.w;
    float lz = 0.f, la = 0.f;
    #pragma unroll
    for (int i = 0; i < 8; ++i){ lz += e[i]; la += a[i]; }
    #pragma unroll
    for (int o = 1; o < 64; o <<= 1){
      lz += __shfl_xor(lz, o, 64);
      la += __shfl_xor(la, o, 64);
    }
    const float c0 = (lz > 0.f) ? 0.3f / lz : 0.f;
    const float c1 = 0.4f / (la + 1e-6f);
    uint4 o4;
    o4.x = pk2(e[0]*c0 + a[0]*c1, e[1]*c0 + a[1]*c1);
    o4.y = pk2(e[2]*c0 + a[2]*c1, e[3]*c0 + a[3]*c1);
    o4.z = pk2(e[4]*c0 + a[4]*c1, e[5]*c0 + a[5]*c1);
    o4.w = pk2(e[6]*c0 + a[6]*c1, e[7]*c0 + a[7]*c1);
    *reinterpret_cast<uint4*>(g_STb + roff) = o4;
  }
}

// ---------------------------------------------------------------------------
// Dispatch 3: streaming attention (r12, accuracy-proven). 512 thr = 8 waves
// = 8 heads; one (b,qtile). Per chunk: S^T=mfma(K,Q) -> exp -> hi/lo bf16
// split -> LDS transpose -> o += V*hi + V*lo, s += V*ST. O = o*(0.3/psum)+s.
// Then fused Wo projection from LDS X tile.
// ---------------------------------------------------------------------------
__global__ __launch_bounds__(512) void attn_kernel(
    const int* __restrict__ mask, const float* __restrict__ bo,
    float* __restrict__ out)
{
  __shared__ unsigned short Pl[8*16*80];    // 20.5 KB: per-wave 16q x (32hi|8pad|32lo)
  __shared__ unsigned short Xl[16*264];     //  8.4 KB: X[qrow][n] bf16
  const int bid = blockIdx.x;
  const int b  = bid & 15;                  // same-b -> same XCD (L2 K/V/ST reuse)
  const int qt = bid >> 4;
  const int q0 = qt*16;
  const int t  = threadIdx.x;
  const int w  = t >> 6, lane = t & 63;
  const int kl = lane & 15, quad = lane >> 4;
  const int h  = w;
  const size_t bh = (size_t)b*H_ + h;
  const float scale = 0.17677669529663687f;   // 1/sqrt(32)

  const unsigned short* Qp = g_Qb + (bh*N_ + q0)*DK_;
  const unsigned short* Kp = g_Kb + bh*N_*DK_;
  const unsigned short* Vp = g_VT + bh*DK_*N_;
  const unsigned short* Sp = g_STb + ((size_t)(b*N_ + q0))*N_;
  const int* mrow = mask + b*N_;
  const v4f vz = {0.f, 0.f, 0.f, 0.f};

  // Q B-frag: B[d=quad*8+j][q=kl] = Q[q0+kl][quad*8+j]
  const v8s aq = *reinterpret_cast<const v8s*>(Qp + (size_t)kl*DK_ + quad*8);

  unsigned short* Pw = Pl + w*1280;
  v4f o0 = vz, o1 = vz;     // unnormalized sum exp(s)*V  (hi+lo exact)
  v4f s0 = vz, s1 = vz;     // ST*V
  float psum = 0.f;

  #pragma unroll
  for (int c = 0; c < 16; ++c){
    // ---- S^T chunk: keys c*32 + [0,32) ----
    const v8s ak0 = *reinterpret_cast<const v8s*>(Kp + (size_t)(c*32 +      kl)*DK_ + quad*8);
    const v8s ak1 = *reinterpret_cast<const v8s*>(Kp + (size_t)(c*32 + 16 + kl)*DK_ + quad*8);
    v4f t0 = __builtin_amdgcn_mfma_f32_16x16x32_bf16(ak0, aq, vz, 0, 0, 0);
    v4f t1 = __builtin_amdgcn_mfma_f32_16x16x32_bf16(ak1, aq, vz, 0, 0, 0);

    // lane holds S^T[key = c*32 + 16*blk + quad*4 + r][q = kl]
    const int4 mv0 = reinterpret_cast<const int4*>(mrow + c*32)[quad];
    const int4 mv1 = reinterpret_cast<const int4*>(mrow + c*32 + 16)[quad];
    t0[0] = mv0.x ? __expf(t0[0]*scale) : 0.f;
    t0[1] = mv0.y ? __expf(t0[1]*scale) : 0.f;
    t0[2] = mv0.z ? __expf(t0[2]*scale) : 0.f;
    t0[3] = mv0.w ? __expf(t0[3]*scale) : 0.f;
    t1[0] = mv1.x ? __expf(t1[0]*scale) : 0.f;
    t1[1] = mv1.y ? __expf(t1[1]*scale) : 0.f;
    t1[2] = mv1.z ? __expf(t1[2]*scale) : 0.f;
    t1[3] = mv1.w ? __expf(t1[3]*scale) : 0.f;
    psum += (t0[0]+t0[1]) + (t0[2]+t0[3]) + (t1[0]+t1[1]) + (t1[2]+t1[3]);

    // ---- hi/lo bf16 split: p = hi + lo, |err| ~ 2^-18 * p ----
    const unsigned int h00 = pk2(t0[0], t0[1]);
    const unsigned int h01 = pk2(t0[2], t0[3]);
    const unsigned int h10 = pk2(t1[0], t1[1]);
    const unsigned int h11 = pk2(t1[2], t1[3]);
    const unsigned int l00 = pk2(t0[0] - lo16f(h00), t0[1] - hi16f(h00));
    const unsigned int l01 = pk2(t0[2] - lo16f(h01), t0[3] - hi16f(h01));
    const unsigned int l10 = pk2(t1[0] - lo16f(h10), t1[1] - hi16f(h10));
    const unsigned int l11 = pk2(t1[2] - lo16f(h11), t1[3] - hi16f(h11));

    // ---- transpose through LDS (short vecs both ways: TBAA-safe order) ----
    {
      union { unsigned int u[2]; v4s v; } wv;
      wv.u[0] = h00; wv.u[1] = h01;
      *reinterpret_cast<v4s*>(&Pw[kl*80 + quad*4])      = wv.v;
      wv.u[0] = h10; wv.u[1] = h11;
      *reinterpret_cast<v4s*>(&Pw[kl*80 + 16 + quad*4]) = wv.v;
      wv.u[0] = l00; wv.u[1] = l01;
      *reinterpret_cast<v4s*>(&Pw[kl*80 + 40 + quad*4])      = wv.v;
      wv.u[0] = l10; wv.u[1] = l11;
      *reinterpret_cast<v4s*>(&Pw[kl*80 + 40 + 16 + quad*4]) = wv.v;
    }
    // B-frags: P[q=kl][key = c*32 + quad*8 + j]  (same-wave, lgkm-ordered)
    const v8s bph = *reinterpret_cast<const v8s*>(&Pw[kl*80 + quad*8]);
    const v8s bpl = *reinterpret_cast<const v8s*>(&Pw[kl*80 + 40 + quad*8]);
    const v8s bst = *reinterpret_cast<const v8s*>(Sp + (size_t)kl*N_ + c*32 + quad*8);
    const v8s av0 = *reinterpret_cast<const v8s*>(Vp + (size_t)(     kl)*N_ + c*32 + quad*8);
    const v8s av1 = *reinterpret_cast<const v8s*>(Vp + (size_t)(16 + kl)*N_ + c*32 + quad*8);
    o0 = __builtin_amdgcn_mfma_f32_16x16x32_bf16(av0, bph, o0, 0, 0, 0);
    o0 = __builtin_amdgcn_mfma_f32_16x16x32_bf16(av0, bpl, o0, 0, 0, 0);
    s0 = __builtin_amdgcn_mfma_f32_16x16x32_bf16(av0, bst, s0, 0, 0, 0);
    o1 = __builtin_amdgcn_mfma_f32_16x16x32_bf16(av1, bph, o1, 0, 0, 0);
    o1 = __builtin_amdgcn_mfma_f32_16x16x32_bf16(av1, bpl, o1, 0, 0, 0);
    s1 = __builtin_amdgcn_mfma_f32_16x16x32_bf16(av1, bst, s1, 0, 0, 0);
  }

  // ---- column sum over q=kl (lanes kl, kl+16, kl+32, kl+48), then scale ----
  psum += __shfl_xor(psum, 16, 64);
  psum += __shfl_xor(psum, 32, 64);
  const float inv = (psum > 0.f) ? 0.3f / psum : 0.f;
  #pragma unroll
  for (int r = 0; r < 4; ++r){
    o0[r] = o0[r]*inv + s0[r];
    o1[r] = o1[r]*inv + s1[r];
  }

  // ---- X[q=kl][h*32 + d'] bf16 into LDS (lane holds O^T[d'=quad*4+r][q=kl]) ----
  {
    unsigned short* xr = Xl + kl*264 + h*32;
    *reinterpret_cast<unsigned int*>(&xr[quad*4])          = pk2(o0[0], o0[1]);
    *reinterpret_cast<unsigned int*>(&xr[quad*4 + 2])      = pk2(o0[2], o0[3]);
    *reinterpret_cast<unsigned int*>(&xr[16 + quad*4])     = pk2(o1[0], o1[1]);
    *reinterpret_cast<unsigned int*>(&xr[16 + quad*4 + 2]) = pk2(o1[2], o1[3]);
  }
  __syncthreads();

  // ---- Phase C: out = X @ Wo^T + bo; wave w -> n in [w*32, w*32+32) ----
  {
    const unsigned short* WoB = g_Wb + 3*65536;
    const int n0 = w*32;
    v4f a20 = vz, a21 = vz;
    #pragma unroll
    for (int k0 = 0; k0 < 256; k0 += 32){
      const v8s af  = *reinterpret_cast<const v8s*>(&Xl[kl*264 + k0 + quad*8]);
      const v8s wf0 = *reinterpret_cast<const v8s*>(WoB + (size_t)(n0 + kl)*256 + k0 + quad*8);
      const v8s wf1 = *reinterpret_cast<const v8s*>(WoB + (size_t)(n0 + 16 + kl)*256 + k0 + quad*8);
      a20 = __builtin_amdgcn_mfma_f32_16x16x32_bf16(af, wf0, a20, 0, 0, 0);
      a21 = __builtin_amdgcn_mfma_f32_16x16x32_bf16(af, wf1, a21, 0, 0, 0);
    }
    const int n_0 = n0 + kl, n_1 = n0 + 16 + kl;
    const float b0v = bo[n_0], b1v = bo[n_1];
    #pragma unroll
    for (int r = 0; r < 4; ++r){
      const size_t m = (size_t)(b*N_ + q0 + quad*4 + r);
      out[m*256 + n_0] = a20[r] + b0v;
      out[m*256 + n_1] = a21[r] + b1v;
    }
  }
}

extern "C" void kernel_launch(void* const* d_in, const int* in_sizes, int n_in,
                              void* d_out, int out_size, void* d_ws, size_t ws_size,
                              hipStream_t stream)
{
  const float* query = (const float*)d_in[0];
  const float* key_  = (const float*)d_in[1];
  const float* value = (const float*)d_in[2];
  const float* adjm  = (const float*)d_in[3];
  const float* dist  = (const float*)d_in[4];
  // d_in[5] = edges_att (unused)
  const int*   mask  = (const int*)d_in[6];
  const float* Wq = (const float*)d_in[7];  const float* bq = (const float*)d_in[8];
  const float* Wk = (const float*)d_in[9];  const float* bk = (const float*)d_in[10];
  const float* Wv = (const float*)d_in[11]; const float* bv = (const float*)d_in[12];
  const float* Wo = (const float*)d_in[13]; const float* bo = (const float*)d_in[14];

  conv_w<<<256, 256, 0, stream>>>(Wq, Wk, Wv, Wo);
  fused_mid<<<3584, 256, 0, stream>>>(query, key_, value, dist, adjm, mask,
                                      bq, bk, bv);
  attn_kernel<<<512, 512, 0, stream>>>(mask, bo, (float*)d_out);
}